// Round 7
// baseline (1173.743 us; speedup 1.0000x reference)
//
#include <hip/hip_runtime.h>
#include <cstdint>

constexpr int N_FEAT  = 8;
constexpr int E_FEAT  = 4;
constexpr int NUM_IN  = 2 * (N_FEAT + 2) + E_FEAT + 1;  // 25
constexpr int NUM_OUT = 2 * N_FEAT + E_FEAT;            // 20
constexpr int BLK     = 256;
constexpr int EPT     = 2;      // edges per thread
constexpr int RSTRIDE = 28;     // LDS row stride (25 padded to 7 float4s)

// Evidence trail (dispatch-us / VALUBusy):
//   SMEM weights (s_load->SGPR):   77 / 40%  -- lgkmcnt(0) drains, convoying
//   VMEM weights (global->VGPR):  171 / 19%  -- 281 x ~200cy loads, no pipelining
//   LDS weights, EPT=1:            70 / 44%  -- LDS return bus 256B/cy shared by
//       4 SIMDs: 4x281x4cy = 4500 LDS-cy per 2250 FMA-cy -> 2x oversubscribed.
// Fix: EPT=2 amortizes every weight read over 2 edges -> LDS:FMA ~ 1:1.
// Rounds 2/4's EPT=2 failed with arrays (unroll budget gave up -> runtime
// indices -> scratch, VGPR pinned 52). This version is macro-generated
// straight-line code over NAMED SCALARS: no loops, no arrays, nothing to spill.

#define REP25(F) F(0) F(1) F(2) F(3) F(4) F(5) F(6) F(7) F(8) F(9) F(10) F(11) \
                 F(12) F(13) F(14) F(15) F(16) F(17) F(18) F(19) F(20) F(21) F(22) F(23) F(24)
#define REP20(F) F(0) F(1) F(2) F(3) F(4) F(5) F(6) F(7) F(8) F(9) F(10) F(11) \
                 F(12) F(13) F(14) F(15) F(16) F(17) F(18) F(19)

#define DECLX(j) float x0_##j, x1_##j;
#define DECLH(j) float h0_##j, h1_##j;
#define DECLY(j) float y0_##j, y1_##j;

// Gather 25 features for edge ee into named scalars P##0..P##24.
#define LOADX(ee, P)                                                          \
  {                                                                           \
    const float4* A4_ = reinterpret_cast<const float4*>(a_data) + 2 * (size_t)(ee); \
    const float4* B4_ = reinterpret_cast<const float4*>(b_data) + 2 * (size_t)(ee); \
    const float4 A0_ = A4_[0], A1_ = A4_[1];                                  \
    const float4 Bv0_ = B4_[0], Bv1_ = B4_[1];                                \
    const float4 Ev_ = reinterpret_cast<const float4*>(e_data)[(ee)];         \
    P##0  = r[(ee)];                                                          \
    P##1  = A0_.x;  P##2  = A0_.y;  P##3  = A0_.z;  P##4  = A0_.w;            \
    P##5  = A1_.x;  P##6  = A1_.y;  P##7  = A1_.z;  P##8  = A1_.w;            \
    P##9  = a_mat[(ee)];                                                      \
    P##10 = a_inf[(ee)];                                                      \
    P##11 = Bv0_.x; P##12 = Bv0_.y; P##13 = Bv0_.z; P##14 = Bv0_.w;           \
    P##15 = Bv1_.x; P##16 = Bv1_.y; P##17 = Bv1_.z; P##18 = Bv1_.w;           \
    P##19 = b_mat[(ee)];                                                      \
    P##20 = b_inf[(ee)];                                                      \
    P##21 = Ev_.x;  P##22 = Ev_.y;  P##23 = Ev_.z;  P##24 = Ev_.w;            \
  }

// One output row j of layer L (7 aligned ds_read_b128, 25 weights),
// accumulated for BOTH edges (XA=x0_, XB=x1_), relu, into OA##j / OB##j.
#define MLPROW(SW4, SB, j, XA, XB, OA, OB)                                    \
  {                                                                           \
    const float4 q0_ = SW4[(j)*7 + 0], q1_ = SW4[(j)*7 + 1];                  \
    const float4 q2_ = SW4[(j)*7 + 2], q3_ = SW4[(j)*7 + 3];                  \
    const float4 q4_ = SW4[(j)*7 + 4], q5_ = SW4[(j)*7 + 5];                  \
    const float4 q6_ = SW4[(j)*7 + 6];                                        \
    float aA_ = SB[(j)], aB_ = aA_;                                           \
    aA_ = fmaf(q0_.x, XA##0,  aA_);  aB_ = fmaf(q0_.x, XB##0,  aB_);          \
    aA_ = fmaf(q0_.y, XA##1,  aA_);  aB_ = fmaf(q0_.y, XB##1,  aB_);          \
    aA_ = fmaf(q0_.z, XA##2,  aA_);  aB_ = fmaf(q0_.z, XB##2,  aB_);          \
    aA_ = fmaf(q0_.w, XA##3,  aA_);  aB_ = fmaf(q0_.w, XB##3,  aB_);          \
    aA_ = fmaf(q1_.x, XA##4,  aA_);  aB_ = fmaf(q1_.x, XB##4,  aB_);          \
    aA_ = fmaf(q1_.y, XA##5,  aA_);  aB_ = fmaf(q1_.y, XB##5,  aB_);          \
    aA_ = fmaf(q1_.z, XA##6,  aA_);  aB_ = fmaf(q1_.z, XB##6,  aB_);          \
    aA_ = fmaf(q1_.w, XA##7,  aA_);  aB_ = fmaf(q1_.w, XB##7,  aB_);          \
    aA_ = fmaf(q2_.x, XA##8,  aA_);  aB_ = fmaf(q2_.x, XB##8,  aB_);          \
    aA_ = fmaf(q2_.y, XA##9,  aA_);  aB_ = fmaf(q2_.y, XB##9,  aB_);          \
    aA_ = fmaf(q2_.z, XA##10, aA_);  aB_ = fmaf(q2_.z, XB##10, aB_);          \
    aA_ = fmaf(q2_.w, XA##11, aA_);  aB_ = fmaf(q2_.w, XB##11, aB_);          \
    aA_ = fmaf(q3_.x, XA##12, aA_);  aB_ = fmaf(q3_.x, XB##12, aB_);          \
    aA_ = fmaf(q3_.y, XA##13, aA_);  aB_ = fmaf(q3_.y, XB##13, aB_);          \
    aA_ = fmaf(q3_.z, XA##14, aA_);  aB_ = fmaf(q3_.z, XB##14, aB_);          \
    aA_ = fmaf(q3_.w, XA##15, aA_);  aB_ = fmaf(q3_.w, XB##15, aB_);          \
    aA_ = fmaf(q4_.x, XA##16, aA_);  aB_ = fmaf(q4_.x, XB##16, aB_);          \
    aA_ = fmaf(q4_.y, XA##17, aA_);  aB_ = fmaf(q4_.y, XB##17, aB_);          \
    aA_ = fmaf(q4_.z, XA##18, aA_);  aB_ = fmaf(q4_.z, XB##18, aB_);          \
    aA_ = fmaf(q4_.w, XA##19, aA_);  aB_ = fmaf(q4_.w, XB##19, aB_);          \
    aA_ = fmaf(q5_.x, XA##20, aA_);  aB_ = fmaf(q5_.x, XB##20, aB_);          \
    aA_ = fmaf(q5_.y, XA##21, aA_);  aB_ = fmaf(q5_.y, XB##21, aB_);          \
    aA_ = fmaf(q5_.z, XA##22, aA_);  aB_ = fmaf(q5_.z, XB##22, aB_);          \
    aA_ = fmaf(q5_.w, XA##23, aA_);  aB_ = fmaf(q5_.w, XB##23, aB_);          \
    aA_ = fmaf(q6_.x, XA##24, aA_);  aB_ = fmaf(q6_.x, XB##24, aB_);          \
    OA##j = fmaxf(aA_, 0.0f);        OB##j = fmaxf(aB_, 0.0f);                \
  }

#define L1ROW(j) MLPROW(sW14, sB1, j, x0_, x1_, h0_, h1_)
#define L2ROW(j) MLPROW(sW24, sB2, j, h0_, h1_, y0_, y1_)

// Store the 20 outputs of edge ee (prefix P = y0_ / y1_).
#define STOREY(ee, P)                                                         \
  {                                                                           \
    float4* o0_ = reinterpret_cast<float4*>(out) + 2 * (size_t)(ee);          \
    o0_[0] = make_float4(P##0,  P##1,  P##2,  P##3);                          \
    o0_[1] = make_float4(P##4,  P##5,  P##6,  P##7);                          \
    float4* o1_ = reinterpret_cast<float4*>(out + (size_t)8 * E) + 2 * (size_t)(ee); \
    o1_[0] = make_float4(P##8,  P##9,  P##10, P##11);                         \
    o1_[1] = make_float4(P##12, P##13, P##14, P##15);                         \
    reinterpret_cast<float4*>(out + (size_t)16 * E)[(ee)] =                   \
        make_float4(P##16, P##17, P##18, P##19);                              \
  }

__global__ __launch_bounds__(BLK)
__attribute__((amdgpu_waves_per_eu(3, 4)))
void edge_mlp(
    const float* __restrict__ r,
    const float* __restrict__ a_data,
    const float* __restrict__ a_mat,
    const float* __restrict__ a_inf,
    const float* __restrict__ b_data,
    const float* __restrict__ b_mat,
    const float* __restrict__ b_inf,
    const float* __restrict__ e_data,
    const float* __restrict__ W1,   // (25,25) row-major fp32
    const float* __restrict__ B1,   // (25,)
    const float* __restrict__ W2,   // (20,25) row-major
    const float* __restrict__ B2,   // (20,)
    float*       __restrict__ out,  // fp32, 3 segments concatenated
    int E) {
  __shared__ __align__(16) float sW1[NUM_IN  * RSTRIDE];  // 700 floats
  __shared__ __align__(16) float sW2[NUM_OUT * RSTRIDE];  // 560 floats
  __shared__ float sB1[NUM_IN];
  __shared__ float sB2[NUM_OUT];

  const int tid = threadIdx.x;
  // ---- stage weights into LDS, rows padded to 28 floats (7 aligned f4) ----
  for (int idx = tid; idx < NUM_IN * NUM_IN; idx += BLK)
    sW1[(idx / NUM_IN) * RSTRIDE + (idx % NUM_IN)] = W1[idx];
  for (int idx = tid; idx < NUM_OUT * NUM_IN; idx += BLK)
    sW2[(idx / NUM_IN) * RSTRIDE + (idx % NUM_IN)] = W2[idx];
  if (tid < NUM_IN)  sB1[tid] = B1[tid];
  if (tid < NUM_OUT) sB2[tid] = B2[tid];
  __syncthreads();

  const float4* sW14 = reinterpret_cast<const float4*>(sW1);
  const float4* sW24 = reinterpret_cast<const float4*>(sW2);

  const int base = blockIdx.x * (BLK * EPT);
  const int e0   = base + tid;
  if (e0 >= E) return;
  int e1         = base + BLK + tid;
  const bool p1  = (e1 < E);
  if (!p1) e1 = e0;   // clamp: tail block's second-edge loads stay in-bounds

  // ---- gather features for both edges (named scalars, nothing to spill) ----
  REP25(DECLX)
  LOADX(e0, x0_)
  LOADX(e1, x1_)

  // ---- layer 1: 25 rows x 2 edges; weights read ONCE per row pair ----
  REP25(DECLH)
  REP25(L1ROW)

  // ---- layer 2: 20 rows x 2 edges ----
  REP20(DECLY)
  REP20(L2ROW)

  // ---- store both edges ----
  STOREY(e0, y0_)
  if (p1) STOREY(e1, y1_)
}

extern "C" void kernel_launch(void* const* d_in, const int* in_sizes, int n_in,
                              void* d_out, int out_size, void* d_ws, size_t ws_size,
                              hipStream_t stream) {
  const float* r      = (const float*)d_in[0];
  const float* a_data = (const float*)d_in[1];
  const float* a_mat  = (const float*)d_in[2];
  const float* a_inf  = (const float*)d_in[3];
  const float* b_data = (const float*)d_in[4];
  const float* b_mat  = (const float*)d_in[5];
  const float* b_inf  = (const float*)d_in[6];
  const float* e_data = (const float*)d_in[7];
  const float* W1     = (const float*)d_in[8];
  const float* B1     = (const float*)d_in[9];
  const float* W2     = (const float*)d_in[10];
  const float* B2     = (const float*)d_in[11];
  int E = in_sizes[0];

  const int epb = BLK * EPT;
  edge_mlp<<<(E + epb - 1) / epb, BLK, 0, stream>>>(
      r, a_data, a_mat, a_inf, b_data, b_mat, b_inf, e_data,
      W1, B1, W2, B2, (float*)d_out, E);
}